// Round 5
// baseline (373.315 us; speedup 1.0000x reference)
//
#include <hip/hip_runtime.h>
#include <stdint.h>

#define BATCH 2000000
#define NHID  14
#define NT    6                         // 16-row n-tiles per wave -> 96 rows/wave
#define NWAVE 12                        // 768-thread block: 3 waves/SIMD (reg cap 170)
#define ROWS_PER_BLOCK (NWAVE * 16 * NT)                         // 1152
#define NTILES ((BATCH + ROWS_PER_BLOCK - 1) / ROWS_PER_BLOCK)   // 1737
#define NSLOT 118                       // 4 (L0) + 14*8 (hidden) + 2 (out) x32 A-fragments
#define LDS_BYTES (NSLOT * 64 * 16)     // 120832 B -> 1 block/CU

typedef float    v4f  __attribute__((ext_vector_type(4)));
typedef _Float16 v8h  __attribute__((ext_vector_type(8)));
typedef __fp16   v2p  __attribute__((ext_vector_type(2)));  // matches cvt_pkrtz return
typedef uint32_t v4u  __attribute__((ext_vector_type(4)));

// x32 MFMA layouts: A[m=lane&15][k=quad*8+j], B[k=quad*8+j][n=lane&15],
// C/D[row=quad*4+reg][col=lane&15].
// k-permutation: A's k-columns stored permuted so the next-layer B fragment is
// exactly the concatenation of two packed C tiles (no cross-lane ops).
// Slot kappa = 32*t' + 8*q + j holds actual feature kown(kappa):
//   s = 8*t' + j ; kown = 16*(s>>2) + 4*q + (s&3)
__device__ __forceinline__ int kown(int kappa) {
    int s = ((kappa >> 5) << 3) | (kappa & 7);
    int q = (kappa >> 3) & 3;
    return ((s >> 2) << 4) | (q * 4 + (s & 3));
}

__device__ __forceinline__ uint32_t pk(float a, float b) {      // v_cvt_pkrtz_f16_f32
    union { v2p v; uint32_t u; } c;
    c.v = __builtin_amdgcn_cvt_pkrtz(a, b);
    return c.u;
}
__device__ __forceinline__ uint32_t relu_pk(float a, float b) { // pkrtz + v_pk_max_f16
    v2p z = { (__fp16)0.0f, (__fp16)0.0f };
    union { v2p v; uint32_t u; } c;
    c.v = __builtin_amdgcn_cvt_pkrtz(a, b);
    c.v = __builtin_elementwise_max(c.v, z);
    return c.u;
}

// C tiles (4 x v4f) -> two x32 B fragments (relu + f16 pack). 16 VALU ops.
__device__ __forceinline__ void pack2(const v4f* acc, v8h* Bv) {
    union { v4u u; v8h h; } c0, c1;
    c0.u.x = relu_pk(acc[0][0], acc[0][1]);
    c0.u.y = relu_pk(acc[0][2], acc[0][3]);
    c0.u.z = relu_pk(acc[1][0], acc[1][1]);
    c0.u.w = relu_pk(acc[1][2], acc[1][3]);
    c1.u.x = relu_pk(acc[2][0], acc[2][1]);
    c1.u.y = relu_pk(acc[2][2], acc[2][3]);
    c1.u.z = relu_pk(acc[3][0], acc[3][1]);
    c1.u.w = relu_pk(acc[3][2], acc[3][3]);
    Bv[0] = c0.h;
    Bv[1] = c1.h;
}

// g1: first K-half, 4 INDEPENDENT MFMAs (C = 0).
__device__ __forceinline__ void g1(const v8h (&A)[2][4], const v8h* B, v4f (&acc)[4]) {
    const v4f z4 = (v4f){0.f, 0.f, 0.f, 0.f};
    #pragma unroll
    for (int mt = 0; mt < 4; ++mt)
        acc[mt] = __builtin_amdgcn_mfma_f32_16x16x32_f16(A[0][mt], B[0], z4, 0, 0, 0);
}
// g2: second K-half, accumulates onto g1's result.
__device__ __forceinline__ void g2(const v8h (&A)[2][4], const v8h* B, v4f (&acc)[4]) {
    #pragma unroll
    for (int mt = 0; mt < 4; ++mt)
        acc[mt] = __builtin_amdgcn_mfma_f32_16x16x32_f16(A[1][mt], B[1], acc[mt], 0, 0, 0);
}

extern "C" __global__ __launch_bounds__(768, 3)
void mlp16(const float* __restrict__ x,
           const float* __restrict__ W0, const float* __restrict__ b0,
           const float* __restrict__ Wh, const float* __restrict__ bh,
           const float* __restrict__ Wo, const float* __restrict__ bo,
           float* __restrict__ out)
{
    extern __shared__ char smem_raw[];
    v8h* frag = (v8h*)smem_raw;         // [slot][lane], 16 B per lane

    const int tid  = threadIdx.x;
    const int lane = tid & 63;
    const int wv   = tid >> 6;
    const int l15  = lane & 15;
    const int quad = lane >> 4;

    // ------------- one-time weight staging (bias folded at k==50/16) -------------
    for (int s = wv; s < NSLOT; s += NWAVE) {
        float v[8];
        if (s < 4) {                    // layer 0: natural k, K=32 (16 real + bias@16)
            int m = s * 16 + l15;
            #pragma unroll
            for (int j = 0; j < 8; ++j) {
                int kap = quad * 8 + j;
                float val = 0.f;
                if (kap < 16)      { if (m < 50) val = W0[m * 16 + kap]; }
                else if (kap == 16){ if (m < 50) val = b0[m]; else if (m == 50) val = 1.f; }
                v[j] = val;
            }
        } else if (s < 116) {           // hidden: permuted k, bias col 50, identity row 50
            int h = s - 4, l = h >> 3, t = (h >> 2) & 1, mt = h & 3;
            int m = mt * 16 + l15;
            const float* W = Wh + l * 2500;
            #pragma unroll
            for (int j = 0; j < 8; ++j) {
                int ko = kown(t * 32 + quad * 8 + j);
                float val = 0.f;
                if (ko < 50)       { if (m < 50) val = W[m * 50 + ko]; }
                else if (ko == 50) { if (m < 50) val = bh[l * 50 + m]; else if (m == 50) val = 1.f; }
                v[j] = val;
            }
        } else {                        // output: permuted k, bias col 50, m<4
            int t = s - 116, m = l15;
            #pragma unroll
            for (int j = 0; j < 8; ++j) {
                int ko = kown(t * 32 + quad * 8 + j);
                float val = 0.f;
                if (m < 4) { if (ko < 50) val = Wo[m * 50 + ko]; else if (ko == 50) val = bo[m]; }
                v[j] = val;
            }
        }
        v8h fv;
        #pragma unroll
        for (int j = 0; j < 8; ++j) fv[j] = (_Float16)v[j];   // RNE
        frag[s * 64 + lane] = fv;
    }
    __syncthreads();                    // only barrier in the kernel

    const v4f z4 = (v4f){0.f, 0.f, 0.f, 0.f};   // zero C operand

    for (int tile = blockIdx.x; tile < NTILES; tile += gridDim.x) {
        const int rowbase = tile * ROWS_PER_BLOCK + wv * (16 * NT);
        v8h Bv[NT][2];                  // activations, registers only
        v8h A[2][4];                    // ONE loop-carried A buffer (static idx only)

        // hidden layer 0's A-frags issued up front; L0 compute hides the latency
        {
            const v8h* ab = frag + 4 * 64 + lane;
            #pragma unroll
            for (int t = 0; t < 2; ++t)
                #pragma unroll
                for (int mt = 0; mt < 4; ++mt) A[t][mt] = ab[(t * 4 + mt) * 64];
        }

        // ---- layer 0 (K=32: 16 features + bias-one at kappa=16) ----
        {
            v8h A0[4];
            #pragma unroll
            for (int mt = 0; mt < 4; ++mt) A0[mt] = frag[mt * 64 + lane];

            // all 12 x-loads issued before any compute (independent VMEM)
            v4f xa[NT], xb[NT];
            #pragma unroll
            for (int nt = 0; nt < NT; ++nt) {
                int r  = rowbase + nt * 16 + l15;
                int rc = r < BATCH ? r : BATCH - 1;
                if (quad < 2) {
                    const float* xp = x + (size_t)rc * 16 + quad * 8;
                    xa[nt] = *(const v4f*)xp;
                    xb[nt] = *(const v4f*)(xp + 4);
                }
            }
            #pragma unroll
            for (int nt = 0; nt < NT; ++nt) {
                union { v4u u; v8h h; } bx;
                bx.u = (v4u){0u, 0u, 0u, 0u};
                if (quad < 2) {
                    bx.u.x = pk(xa[nt][0], xa[nt][1]);
                    bx.u.y = pk(xa[nt][2], xa[nt][3]);
                    bx.u.z = pk(xb[nt][0], xb[nt][1]);
                    bx.u.w = pk(xb[nt][2], xb[nt][3]);
                } else if (quad == 2) {
                    bx.u.x = 0x3C00u;   // f16 1.0 at kappa=16 (bias slot)
                }
                v4f acc[4];
                #pragma unroll
                for (int mt = 0; mt < 4; ++mt)
                    acc[mt] = __builtin_amdgcn_mfma_f32_16x16x32_f16(A0[mt], bx.h, z4, 0, 0, 0);
                pack2(acc, Bv[nt]);     // relu + pack: C tiles -> x32 B frags
            }
        }

        // ---- 14 hidden layers: 3 accumulator chains in flight, no SGB.
        //      Next layer's ds_reads issued after last A-use, covered by packs. ----
        for (int l = 0; l < NHID; ++l) {
            v4f a0[4], a1[4], a2[4], a3[4];     // named acc sets, peak 3 live
            g1(A, Bv[0], a0);  g1(A, Bv[1], a1);  g1(A, Bv[2], a2);   // 12 indep MFMA
            g2(A, Bv[0], a0);  g2(A, Bv[1], a1);  g2(A, Bv[2], a2);   // dep dist ~11 MFMA
            pack2(a0, Bv[0]);  g1(A, Bv[3], a3);
            pack2(a1, Bv[1]);  g1(A, Bv[4], a0);
            pack2(a2, Bv[2]);  g1(A, Bv[5], a1);
            g2(A, Bv[3], a3);  g2(A, Bv[4], a0);  g2(A, Bv[5], a1);
            // A dead now: reload for layer l+1 (or output frags); the 3 packs
            // below (~96 VALU cyc) cover the LDS read latency.
            if (l + 1 < NHID) {
                const v8h* ab = frag + (4 + (l + 1) * 8) * 64 + lane;
                #pragma unroll
                for (int t = 0; t < 2; ++t)
                    #pragma unroll
                    for (int mt = 0; mt < 4; ++mt) A[t][mt] = ab[(t * 4 + mt) * 64];
            } else {
                A[0][0] = frag[116 * 64 + lane];    // output-layer frags
                A[0][1] = frag[117 * 64 + lane];
            }
            pack2(a3, Bv[3]);  pack2(a0, Bv[4]);  pack2(a1, Bv[5]);
        }

        // ---- output layer: 2 MFMA per n-tile, 3 chains in flight ----
        {
            v4f o0, o1, o2;
            o0 = __builtin_amdgcn_mfma_f32_16x16x32_f16(A[0][0], Bv[0][0], z4, 0, 0, 0);
            o1 = __builtin_amdgcn_mfma_f32_16x16x32_f16(A[0][0], Bv[1][0], z4, 0, 0, 0);
            o2 = __builtin_amdgcn_mfma_f32_16x16x32_f16(A[0][0], Bv[2][0], z4, 0, 0, 0);
            o0 = __builtin_amdgcn_mfma_f32_16x16x32_f16(A[0][1], Bv[0][1], o0, 0, 0, 0);
            o1 = __builtin_amdgcn_mfma_f32_16x16x32_f16(A[0][1], Bv[1][1], o1, 0, 0, 0);
            o2 = __builtin_amdgcn_mfma_f32_16x16x32_f16(A[0][1], Bv[2][1], o2, 0, 0, 0);
            int r0 = rowbase + 0 * 16 + l15;
            int r1 = rowbase + 1 * 16 + l15;
            int r2 = rowbase + 2 * 16 + l15;
            if (quad == 0 && r0 < BATCH) *(v4f*)(out + (size_t)r0 * 4) = o0;
            if (quad == 0 && r1 < BATCH) *(v4f*)(out + (size_t)r1 * 4) = o1;
            if (quad == 0 && r2 < BATCH) *(v4f*)(out + (size_t)r2 * 4) = o2;
            o0 = __builtin_amdgcn_mfma_f32_16x16x32_f16(A[0][0], Bv[3][0], z4, 0, 0, 0);
            o1 = __builtin_amdgcn_mfma_f32_16x16x32_f16(A[0][0], Bv[4][0], z4, 0, 0, 0);
            o2 = __builtin_amdgcn_mfma_f32_16x16x32_f16(A[0][0], Bv[5][0], z4, 0, 0, 0);
            o0 = __builtin_amdgcn_mfma_f32_16x16x32_f16(A[0][1], Bv[3][1], o0, 0, 0, 0);
            o1 = __builtin_amdgcn_mfma_f32_16x16x32_f16(A[0][1], Bv[4][1], o1, 0, 0, 0);
            o2 = __builtin_amdgcn_mfma_f32_16x16x32_f16(A[0][1], Bv[5][1], o2, 0, 0, 0);
            r0 = rowbase + 3 * 16 + l15;
            r1 = rowbase + 4 * 16 + l15;
            r2 = rowbase + 5 * 16 + l15;
            if (quad == 0 && r0 < BATCH) *(v4f*)(out + (size_t)r0 * 4) = o0;
            if (quad == 0 && r1 < BATCH) *(v4f*)(out + (size_t)r1 * 4) = o1;
            if (quad == 0 && r2 < BATCH) *(v4f*)(out + (size_t)r2 * 4) = o2;
        }
    }
}

extern "C" void kernel_launch(void* const* d_in, const int* in_sizes, int n_in,
                              void* d_out, int out_size, void* d_ws, size_t ws_size,
                              hipStream_t stream)
{
    (void)in_sizes; (void)n_in; (void)d_ws; (void)ws_size; (void)out_size;
    (void)hipFuncSetAttribute(reinterpret_cast<const void*>(mlp16),
                              hipFuncAttributeMaxDynamicSharedMemorySize, LDS_BYTES);
    mlp16<<<256, 768, LDS_BYTES, stream>>>(
        (const float*)d_in[0], (const float*)d_in[1], (const float*)d_in[2],
        (const float*)d_in[3], (const float*)d_in[4], (const float*)d_in[5],
        (const float*)d_in[6], (float*)d_out);
}

// Round 6
// 318.702 us; speedup vs baseline: 1.1714x; 1.1714x over previous
//
#include <hip/hip_runtime.h>
#include <stdint.h>

#define BATCH 2000000
#define NHID  14
#define NWAVE 12                        // 768-thread block: 3 waves/SIMD
#define ROWS_PER_WAVE 96                // 3 tiles of 32 rows
#define ROWS_PER_BLOCK (NWAVE * ROWS_PER_WAVE)                   // 1152
#define NTILES ((BATCH + ROWS_PER_BLOCK - 1) / ROWS_PER_BLOCK)   // 1737
#define NSLOT 120                       // 4 (L0) + 14*8 (hidden) + 4 (out) 32x32x16 A-frags
#define LDS_BYTES (NSLOT * 64 * 16)     // 122880 B -> 1 block/CU

typedef float    v4f  __attribute__((ext_vector_type(4)));
typedef float    v16f __attribute__((ext_vector_type(16)));
typedef _Float16 v8h  __attribute__((ext_vector_type(8)));
typedef __fp16   v2p  __attribute__((ext_vector_type(2)));  // matches cvt_pkrtz return
typedef uint32_t v4u  __attribute__((ext_vector_type(4)));

// 32x32x16 MFMA layouts (gfx950):
//   A[m=lane&31][k=8*(lane>>5)+j]   (j=0..7, v8h)
//   B[k=8*(lane>>5)+j][n=lane&31]
//   C/D[row=(reg&3)+8*(reg>>2)+4*(lane>>5)][col=lane&31]  (v16f)
// k-permutation: K-step t consumes activation FEATURE
//   f(t,hi,j) = 16*t + (j&3) + 8*(j>>2) + 4*hi        (hi = lane>>5)
// chosen so that C reg r of subtile s (feature 32*s + (r&3)+8*(r>>2)+4*hi)
// packs DIRECTLY into next-layer B frags:
//   B[2s+0] half j = relu(C_s[j]),  B[2s+1] half j = relu(C_s[8+j])
// (batch col = lane&31 and hi-group both align -> zero cross-lane ops).
// Bias folded as feature 50 (constant 1.0 propagated via identity row m=50).

__device__ __forceinline__ uint32_t pk(float a, float b) {      // v_cvt_pkrtz_f16_f32
    union { v2p v; uint32_t u; } c;
    c.v = __builtin_amdgcn_cvt_pkrtz(a, b);
    return c.u;
}
__device__ __forceinline__ uint32_t relu_pk(float a, float b) { // pkrtz + v_pk_max_f16
    v2p z = { (__fp16)0.0f, (__fp16)0.0f };
    union { v2p v; uint32_t u; } c;
    c.v = __builtin_amdgcn_cvt_pkrtz(a, b);
    c.v = __builtin_elementwise_max(c.v, z);
    return c.u;
}

__device__ __forceinline__ v16f mfma32(v8h a, v8h b, v16f c) {
    return __builtin_amdgcn_mfma_f32_32x32x16_f16(a, b, c, 0, 0, 0);
}

__device__ __forceinline__ v8h pack_lo(const v16f& c) {   // relu+pack C regs 0..7
    union { v4u u; v8h h; } r;
    r.u.x = relu_pk(c[0], c[1]);
    r.u.y = relu_pk(c[2], c[3]);
    r.u.z = relu_pk(c[4], c[5]);
    r.u.w = relu_pk(c[6], c[7]);
    return r.h;
}
__device__ __forceinline__ v8h pack_hi(const v16f& c) {   // relu+pack C regs 8..15
    union { v4u u; v8h h; } r;
    r.u.x = relu_pk(c[8],  c[9]);
    r.u.y = relu_pk(c[10], c[11]);
    r.u.z = relu_pk(c[12], c[13]);
    r.u.w = relu_pk(c[14], c[15]);
    return r.h;
}

// One hidden layer for one 32-row tile: 8 MFMA_32 (2 indep chains of 4) + 32 VALU.
__device__ __forceinline__ void hidden_tile(const v8h (&A)[8], v8h (&B)[4]) {
    const v16f z = {0.f,0.f,0.f,0.f,0.f,0.f,0.f,0.f,0.f,0.f,0.f,0.f,0.f,0.f,0.f,0.f};
    v16f c0 = mfma32(A[0], B[0], z);        // subtile 0 (features 0-31)
    v16f c1 = mfma32(A[4], B[0], z);        // subtile 1 (features 32-63)
    c0 = mfma32(A[1], B[1], c0);  c1 = mfma32(A[5], B[1], c1);
    c0 = mfma32(A[2], B[2], c0);  c1 = mfma32(A[6], B[2], c1);
    c0 = mfma32(A[3], B[3], c0);  c1 = mfma32(A[7], B[3], c1);
    B[0] = pack_lo(c0);  B[1] = pack_hi(c0);
    B[2] = pack_lo(c1);  B[3] = pack_hi(c1);
}

// Layer 0 for one 32-row tile: dense x loads (all 64 lanes), 4 MFMA_32.
__device__ __forceinline__ void l0_tile(const v8h (&A0)[4],
                                        const float* __restrict__ x,
                                        int r, int hi, v8h (&B)[4]) {
    int rc = r < BATCH ? r : BATCH - 1;
    const float* xp = x + (size_t)rc * 16 + hi * 4;
    v4f xa = *(const v4f*)xp;               // features 4hi..4hi+3
    v4f xb = *(const v4f*)(xp + 8);         // features 8+4hi..11+4hi
    union { v4u u; v8h h; } b0;
    b0.u.x = pk(xa[0], xa[1]);
    b0.u.y = pk(xa[2], xa[3]);
    b0.u.z = pk(xb[0], xb[1]);
    b0.u.w = pk(xb[2], xb[3]);
    union { v4u u; v8h h; } b1;             // t=1: bias-one at f==16 (hi=0, j=0)
    b1.u = (v4u){0u, 0u, 0u, 0u};
    if (hi == 0) b1.u.x = 0x3C00u;          // f16 1.0 in half 0
    const v16f z = {0.f,0.f,0.f,0.f,0.f,0.f,0.f,0.f,0.f,0.f,0.f,0.f,0.f,0.f,0.f,0.f};
    v16f c0 = mfma32(A0[0], b0.h, z);       // sub0, K-step 0
    v16f c1 = mfma32(A0[2], b0.h, z);       // sub1, K-step 0
    c0 = mfma32(A0[1], b1.h, c0);           // sub0, K-step 1 (bias)
    c1 = mfma32(A0[3], b1.h, c1);
    B[0] = pack_lo(c0);  B[1] = pack_hi(c0);
    B[2] = pack_lo(c1);  B[3] = pack_hi(c1);
}

// Output layer for one 32-row tile: 4 chained MFMA_32; rows 0-3 live in
// regs 0..3 of hi=0 lanes (rowlocal=(reg&3)+8*(reg>>2)+4hi).
__device__ __forceinline__ void out_tile(const v8h (&Ao)[4], const v8h (&B)[4],
                                         float* __restrict__ out, int r, int hi) {
    const v16f z = {0.f,0.f,0.f,0.f,0.f,0.f,0.f,0.f,0.f,0.f,0.f,0.f,0.f,0.f,0.f,0.f};
    v16f o = mfma32(Ao[0], B[0], z);
    o = mfma32(Ao[1], B[1], o);
    o = mfma32(Ao[2], B[2], o);
    o = mfma32(Ao[3], B[3], o);
    if (hi == 0 && r < BATCH) {
        v4f v = {o[0], o[1], o[2], o[3]};
        *(v4f*)(out + (size_t)r * 4) = v;   // 16B store per row
    }
}

extern "C" __global__ __launch_bounds__(768, 3)
void mlp16(const float* __restrict__ x,
           const float* __restrict__ W0, const float* __restrict__ b0,
           const float* __restrict__ Wh, const float* __restrict__ bh,
           const float* __restrict__ Wo, const float* __restrict__ bo,
           float* __restrict__ out)
{
    extern __shared__ char smem_raw[];
    v8h* frag = (v8h*)smem_raw;         // [slot][lane], 16 B per lane

    const int tid  = threadIdx.x;
    const int lane = tid & 63;
    const int wv   = tid >> 6;
    const int l31  = lane & 31;
    const int hi   = lane >> 5;

    // ------------- one-time weight staging (bias folded at f==50/16) -------------
    // slot map: 0..3   = L0      (sub = s>>1, t = s&1)
    //           4..115 = hidden  (l = (s-4)>>3, i = (s-4)&7, sub = i>>2, t = i&3)
    //           116..119 = out   (t = s-116)
    for (int s = wv; s < NSLOT; s += NWAVE) {
        float v[8];
        if (s < 4) {                    // layer 0: K=32 (16 real + bias@16)
            int sub = s >> 1, t = s & 1;
            int m = sub * 32 + l31;
            #pragma unroll
            for (int j = 0; j < 8; ++j) {
                int f = 16 * t + (j & 3) + 8 * (j >> 2) + 4 * hi;
                float val = 0.f;
                if (f < 16)       { if (m < 50) val = W0[m * 16 + f]; }
                else if (f == 16) { if (m < 50) val = b0[m]; else if (m == 50) val = 1.f; }
                v[j] = val;
            }
        } else if (s < 116) {           // hidden: bias col 50, identity row 50
            int h = s - 4, l = h >> 3, i = h & 7, sub = i >> 2, t = i & 3;
            int m = sub * 32 + l31;
            const float* W = Wh + l * 2500;
            #pragma unroll
            for (int j = 0; j < 8; ++j) {
                int f = 16 * t + (j & 3) + 8 * (j >> 2) + 4 * hi;
                float val = 0.f;
                if (f < 50)       { if (m < 50) val = W[m * 50 + f]; }
                else if (f == 50) { if (m < 50) val = bh[l * 50 + m]; else if (m == 50) val = 1.f; }
                v[j] = val;
            }
        } else {                        // output: m<4 valid, bias col 50
            int t = s - 116, m = l31;
            #pragma unroll
            for (int j = 0; j < 8; ++j) {
                int f = 16 * t + (j & 3) + 8 * (j >> 2) + 4 * hi;
                float val = 0.f;
                if (m < 4) { if (f < 50) val = Wo[m * 50 + f]; else if (f == 50) val = bo[m]; }
                v[j] = val;
            }
        }
        v8h fv;
        #pragma unroll
        for (int j = 0; j < 8; ++j) fv[j] = (_Float16)v[j];   // RNE
        frag[s * 64 + lane] = fv;
    }
    __syncthreads();                    // only barrier in the kernel

    for (int tile = blockIdx.x; tile < NTILES; tile += gridDim.x) {
        const int rowbase = tile * ROWS_PER_BLOCK + wv * ROWS_PER_WAVE;
        v8h B0[4], B1[4], B2[4];        // activations for 3x 32-row tiles (regs only)

        // ---- layer 0 ----
        {
            v8h A0[4];
            #pragma unroll
            for (int i = 0; i < 4; ++i) A0[i] = frag[i * 64 + lane];
            l0_tile(A0, x, rowbase +  0 + l31, hi, B0);
            l0_tile(A0, x, rowbase + 32 + l31, hi, B1);
            l0_tile(A0, x, rowbase + 64 + l31, hi, B2);
        }

        // ---- 14 hidden layers: 24 MFMA_32 + 96 VALU per wave per layer ----
        for (int l = 0; l < NHID; ++l) {
            v8h A[8];
            const v8h* ab = frag + (4 + l * 8) * 64 + lane;
            #pragma unroll
            for (int i = 0; i < 8; ++i) A[i] = ab[i * 64];    // 8x ds_read_b128
            hidden_tile(A, B0);
            hidden_tile(A, B1);
            hidden_tile(A, B2);
        }

        // ---- output layer ----
        {
            v8h Ao[4];
            #pragma unroll
            for (int i = 0; i < 4; ++i) Ao[i] = frag[(116 + i) * 64 + lane];
            out_tile(Ao, B0, out, rowbase +  0 + l31, hi);
            out_tile(Ao, B1, out, rowbase + 32 + l31, hi);
            out_tile(Ao, B2, out, rowbase + 64 + l31, hi);
        }
    }
}

extern "C" void kernel_launch(void* const* d_in, const int* in_sizes, int n_in,
                              void* d_out, int out_size, void* d_ws, size_t ws_size,
                              hipStream_t stream)
{
    (void)in_sizes; (void)n_in; (void)d_ws; (void)ws_size; (void)out_size;
    (void)hipFuncSetAttribute(reinterpret_cast<const void*>(mlp16),
                              hipFuncAttributeMaxDynamicSharedMemorySize, LDS_BYTES);
    mlp16<<<256, 768, LDS_BYTES, stream>>>(
        (const float*)d_in[0], (const float*)d_in[1], (const float*)d_in[2],
        (const float*)d_in[3], (const float*)d_in[4], (const float*)d_in[5],
        (const float*)d_in[6], (float*)d_out);
}